// Round 1
// baseline (402.011 us; speedup 1.0000x reference)
//
#include <hip/hip_runtime.h>
#include <hip/hip_bf16.h>
#include <math.h>

typedef __bf16 bf16_t;
typedef bf16_t bf16x4 __attribute__((ext_vector_type(4)));
typedef bf16_t bf16x8 __attribute__((ext_vector_type(8)));
typedef float  f32x4  __attribute__((ext_vector_type(4)));

#define SEQ 200
#define SP  208   // S padded to 13 * 16
#define DD  64
#define RS  72    // LDS row stride in bf16 elems (144 B = 36 dwords: 16B-aligned b128, <=2-way banks)

#define MFMA(a, b, c) __builtin_amdgcn_mfma_f32_16x16x32_bf16((a), (b), (c), 0, 0, 0)

__global__ __launch_bounds__(256) void din_kernel(
    const float* __restrict__ em, const float* __restrict__ eu,
    const float* __restrict__ Xu, const float* __restrict__ W1,
    const float* __restrict__ b1, const float* __restrict__ W2,
    const float* __restrict__ b2, const float* __restrict__ W3,
    const float* __restrict__ b3, const float* __restrict__ gam,
    const float* __restrict__ bet, const float* __restrict__ mmean,
    const float* __restrict__ mvar, float* __restrict__ out)
{
  // A1 = Xu (bf16), A2 = em*Xu (bf16), A2 recycled as h1 buffer after stage 1.
  __shared__ __align__(16) bf16_t A1[SP * RS];
  __shared__ __align__(16) bf16_t A2[SP * RS];
  __shared__ float em_s[DD];
  __shared__ float qWp[4][DD];
  __shared__ float qW[DD];
  __shared__ float logits[SP];
  __shared__ float red[8];
  __shared__ float wpool[4][DD];

  const int tid  = threadIdx.x;
  const int b    = blockIdx.x;
  const int lane = tid & 63;
  const int wid  = tid >> 6;
  const int g    = lane >> 4;    // quad group 0..3
  const int l16  = lane & 15;

  // ---- phase 0: em -> LDS, zero pad rows (s = 200..207) ----
  if (tid < DD) em_s[tid] = em[(size_t)b * DD + tid];
  for (int i = tid; i < 8 * DD; i += 256) {
    int r = SEQ + (i >> 6), c = i & 63;
    A1[r * RS + c] = (bf16_t)0.f;
    A2[r * RS + c] = (bf16_t)0.f;
  }

  // ---- B fragments (register-resident, weights are L2-hot) ----
  // stage 1: wave w owns output cols n = 16w..16w+15.
  //   A1 (Xu)    pairs with W1b - W1c  (rows 64..127 minus 128..191)
  //   A2 (em*Xu) pairs with W1d        (rows 192..255)
  const int n1 = 16 * wid + l16;
  bf16x8 bX[2], bQ[2];
  #pragma unroll
  for (int c = 0; c < 2; ++c)
    #pragma unroll
    for (int j = 0; j < 8; ++j) {
      int k = 32 * c + 8 * g + j;
      bX[c][j] = (bf16_t)(W1[(64 + k) * 64 + n1] - W1[(128 + k) * 64 + n1]);
      bQ[c][j] = (bf16_t)(W1[(192 + k) * 64 + n1]);
    }
  // stage 2: every wave does full N=32 for its M-tiles.
  bf16x8 bW2f[2][2];
  #pragma unroll
  for (int c = 0; c < 2; ++c)
    #pragma unroll
    for (int u = 0; u < 2; ++u)
      #pragma unroll
      for (int j = 0; j < 8; ++j) {
        int k = 32 * c + 8 * g + j;
        bW2f[c][u][j] = (bf16_t)(W2[k * 32 + 16 * u + l16]);
      }
  const float b2v0 = b2[l16], b2v1 = b2[16 + l16];
  const float w3v0 = W3[l16], w3v1 = W3[16 + l16];
  const float b3s  = b3[0];

  __syncthreads();  // em_s ready

  // ---- phase 1: stage Xu -> A1, em*Xu -> A2 (coalesced float4, bf16 convert) ----
  const float4* Xr = (const float4*)(Xu + (size_t)b * SEQ * DD);
  for (int v = tid; v < SEQ * DD / 4; v += 256) {
    int s  = v >> 4;
    int c4 = (v & 15) * 4;
    float4 x = Xr[v];
    bf16x4 xa, xq;
    xa[0] = (bf16_t)x.x; xa[1] = (bf16_t)x.y;
    xa[2] = (bf16_t)x.z; xa[3] = (bf16_t)x.w;
    xq[0] = (bf16_t)(x.x * em_s[c4 + 0]); xq[1] = (bf16_t)(x.y * em_s[c4 + 1]);
    xq[2] = (bf16_t)(x.z * em_s[c4 + 2]); xq[3] = (bf16_t)(x.w * em_s[c4 + 3]);
    *(bf16x4*)&A1[s * RS + c4] = xa;
    *(bf16x4*)&A2[s * RS + c4] = xq;
  }
  // qW[n] = b1[n] + em @ (W1a + W1c), split over 4 waves
  {
    int j = tid & 63, p = tid >> 6;
    float acc = 0.f;
    for (int d = 16 * p; d < 16 * p + 16; ++d)
      acc += em_s[d] * (W1[d * 64 + j] + W1[(128 + d) * 64 + j]);
    qWp[p][j] = acc;
  }
  __syncthreads();
  if (tid < DD)
    qW[tid] = qWp[0][tid] + qWp[1][tid] + qWp[2][tid] + qWp[3][tid] + b1[tid];
  __syncthreads();  // A1, A2, qW ready

  // ---- stage 1 MFMA: h1_pre[s][n] over 13 M-tiles, K=128 (two 64-chunks) ----
  f32x4 acc[13];
  #pragma unroll
  for (int t = 0; t < 13; ++t) {
    f32x4 a = {0.f, 0.f, 0.f, 0.f};
    int rb = (16 * t + l16) * RS + 8 * g;
    bf16x8 a10 = *(const bf16x8*)&A1[rb];
    bf16x8 a11 = *(const bf16x8*)&A1[rb + 32];
    bf16x8 a20 = *(const bf16x8*)&A2[rb];
    bf16x8 a21 = *(const bf16x8*)&A2[rb + 32];
    a = MFMA(a10, bX[0], a);
    a = MFMA(a11, bX[1], a);
    a = MFMA(a20, bQ[0], a);
    a = MFMA(a21, bQ[1], a);
    acc[t] = a;
  }
  __syncthreads();  // all waves done reading A2 before it becomes h1

  // ---- h1 = relu(acc + qW[n]) -> bf16 into A2 (C-layout: row=16t+4g+r, col=n1) ----
  {
    float qn = qW[n1];
    #pragma unroll
    for (int t = 0; t < 13; ++t)
      #pragma unroll
      for (int r = 0; r < 4; ++r) {
        float v = acc[t][r] + qn;
        v = v > 0.f ? v : 0.f;
        A2[(16 * t + 4 * g + r) * RS + n1] = (bf16_t)v;
      }
  }
  __syncthreads();

  // ---- stage 2 MFMA (K=64, N=32) + stage 3 dot via lane butterfly -> logits ----
  for (int t = wid; t < 13; t += 4) {
    int rb = (16 * t + l16) * RS + 8 * g;
    bf16x8 h0 = *(const bf16x8*)&A2[rb];
    bf16x8 h1 = *(const bf16x8*)&A2[rb + 32];
    f32x4 a0 = {0.f, 0.f, 0.f, 0.f}, a1 = {0.f, 0.f, 0.f, 0.f};
    a0 = MFMA(h0, bW2f[0][0], a0);
    a0 = MFMA(h1, bW2f[1][0], a0);
    a1 = MFMA(h0, bW2f[0][1], a1);
    a1 = MFMA(h1, bW2f[1][1], a1);
    #pragma unroll
    for (int r = 0; r < 4; ++r) {
      float p0 = fmaxf(a0[r] + b2v0, 0.f) * w3v0;
      float p1 = fmaxf(a1[r] + b2v1, 0.f) * w3v1;
      float pr = p0 + p1;                 // this lane's n-partial for row s
      pr += __shfl_xor(pr, 1);
      pr += __shfl_xor(pr, 2);
      pr += __shfl_xor(pr, 4);
      pr += __shfl_xor(pr, 8);            // sum over 16 n-lanes
      if (l16 == 0) logits[16 * t + 4 * g + r] = pr + b3s;
    }
  }
  __syncthreads();

  // ---- softmax over s < 200 ----
  float lv = (tid < SEQ) ? logits[tid] : -INFINITY;
  float mx = lv;
  #pragma unroll
  for (int o = 32; o > 0; o >>= 1) mx = fmaxf(mx, __shfl_xor(mx, o));
  if (lane == 0) red[wid] = mx;
  __syncthreads();
  mx = fmaxf(fmaxf(red[0], red[1]), fmaxf(red[2], red[3]));
  float e = (tid < SEQ) ? __expf(lv - mx) : 0.f;
  float ssum = e;
  #pragma unroll
  for (int o = 32; o > 0; o >>= 1) ssum += __shfl_xor(ssum, o);
  if (lane == 0) red[4 + wid] = ssum;
  __syncthreads();
  float inv = 1.f / (red[4] + red[5] + red[6] + red[7]);
  if (tid < SEQ) logits[tid] = e * inv;   // logits becomes softmax weights
  __syncthreads();

  // ---- pooled[d] = sum_s w_s * Xu[s][d] (Xu bf16 from A1) ----
  {
    int d = tid & 63, p = wid;
    float ps = 0.f;
    for (int s = p; s < SEQ; s += 4)
      ps += logits[s] * (float)A1[s * RS + d];
    wpool[p][d] = ps;
  }
  __syncthreads();

  // ---- BN + concat output: [bn(pooled,em) | eu] = 192 floats per row ----
  if (tid < 192) {
    float v;
    if (tid < 128) {
      float x = (tid < 64)
          ? (wpool[0][tid] + wpool[1][tid] + wpool[2][tid] + wpool[3][tid])
          : em_s[tid - 64];
      v = (x - mmean[tid]) * rsqrtf(mvar[tid] + 1e-3f) * gam[tid] + bet[tid];
    } else {
      v = eu[(size_t)b * 64 + (tid - 128)];
    }
    out[(size_t)b * 192 + tid] = v;
  }
}

extern "C" void kernel_launch(void* const* d_in, const int* in_sizes, int n_in,
                              void* d_out, int out_size, void* d_ws, size_t ws_size,
                              hipStream_t stream) {
  const float* em = (const float*)d_in[0];
  const float* eu = (const float*)d_in[1];
  const float* Xu = (const float*)d_in[2];
  const float* W1 = (const float*)d_in[3];
  const float* b1 = (const float*)d_in[4];
  const float* W2 = (const float*)d_in[5];
  const float* b2 = (const float*)d_in[6];
  const float* W3 = (const float*)d_in[7];
  const float* b3 = (const float*)d_in[8];
  const float* ga = (const float*)d_in[9];
  const float* be = (const float*)d_in[10];
  const float* mm = (const float*)d_in[11];
  const float* mv = (const float*)d_in[12];
  int B = in_sizes[0] / DD;
  din_kernel<<<B, 256, 0, stream>>>(em, eu, Xu, W1, b1, W2, b2, W3, b3,
                                    ga, be, mm, mv, (float*)d_out);
}

// Round 2
// 332.560 us; speedup vs baseline: 1.2088x; 1.2088x over previous
//
#include <hip/hip_runtime.h>
#include <hip/hip_bf16.h>
#include <math.h>

typedef __bf16 bf16_t;
typedef bf16_t bf16x4 __attribute__((ext_vector_type(4)));
typedef bf16_t bf16x8 __attribute__((ext_vector_type(8)));
typedef float  f32x4  __attribute__((ext_vector_type(4)));

#define SEQ 200
#define SP  208   // 13 * 16
#define DD  64
#define RS  72    // LDS row stride (144 B): 16B-aligned b128, 2-way banks = free

#define MFMA(a, b, c) __builtin_amdgcn_mfma_f32_16x16x32_bf16((a), (b), (c), 0, 0, 0)

// ---------------- prep kernel: weight fragments (bf16, transposed) + Q ----------------
// Wbc_t[n][k] = W1b - W1c ; W1d_t[n][k] = W1d ; W2_t[n][k] = W2^T ; Q[b][n] = b1 + em@(W1a+W1c)
__global__ __launch_bounds__(256) void prep_kernel(
    const float* __restrict__ em, const float* __restrict__ W1,
    const float* __restrict__ b1, const float* __restrict__ W2,
    bf16_t* __restrict__ Wbc, bf16_t* __restrict__ W1dt,
    bf16_t* __restrict__ W2t, float* __restrict__ Q)
{
  const int tid = threadIdx.x;
  if (blockIdx.x == 0) {
    for (int i = tid; i < 64 * 64; i += 256) {
      int n = i >> 6, k = i & 63;
      Wbc[i]  = (bf16_t)(W1[(64 + k) * 64 + n] - W1[(128 + k) * 64 + n]);
      W1dt[i] = (bf16_t)(W1[(192 + k) * 64 + n]);
    }
    for (int i = tid; i < 32 * 64; i += 256) {
      int n = i >> 6, k = i & 63;
      W2t[i] = (bf16_t)(W2[k * 32 + n]);
    }
  } else {
    int b = (blockIdx.x - 1) * 4 + (tid >> 6);
    int n = tid & 63;
    float acc = b1[n];
    for (int d = 0; d < 64; ++d)
      acc += em[(size_t)b * 64 + d] * (W1[d * 64 + n] + W1[(128 + d) * 64 + n]);
    Q[(size_t)b * 64 + n] = acc;
  }
}

// ---------------- main kernel: one block per batch row ----------------
__global__ __launch_bounds__(256, 4) void din_kernel(
    const float* __restrict__ em, const float* __restrict__ eu,
    const float* __restrict__ Xu, const float* __restrict__ b2,
    const float* __restrict__ W3, const float* __restrict__ b3,
    const float* __restrict__ gam, const float* __restrict__ bet,
    const float* __restrict__ mmean, const float* __restrict__ mvar,
    const bf16_t* __restrict__ Wbc, const bf16_t* __restrict__ W1dt,
    const bf16_t* __restrict__ W2t, const float* __restrict__ Q,
    float* __restrict__ out)
{
  // A: Xu (bf16) for stage-1 MFMA -> recycled as h1 buffer -> recycled as pooling scratch
  __shared__ __align__(16) bf16_t A[SP * RS];          // 29952 B
  __shared__ float logits[SP];
  __shared__ float red[8];
  float* part = (float*)A;                             // overlay after stage-2

  const int tid  = threadIdx.x;
  const int b    = blockIdx.x;
  const int lane = tid & 63;
  const int wid  = tid >> 6;
  const int g    = lane >> 4;
  const int l16  = lane & 15;
  const int n1   = 16 * wid + l16;

  // zero the pad rows (s = 200..207)
  for (int i = tid; i < 8 * DD; i += 256) {
    int r = SEQ + (i >> 6), c = i & 63;
    A[r * RS + c] = (bf16_t)0.f;
  }

  // ---- fragments from precomputed transposed bf16 weights ----
  // B' = (W1b - W1c) + diag(em) * W1d, fragment k = 32c + 8g + j, col n1
  const bf16x8* Wbc8  = (const bf16x8*)Wbc;
  const bf16x8* W1dt8 = (const bf16x8*)W1dt;
  const bf16x8* W2t8  = (const bf16x8*)W2t;
  bf16x8 bB[2];
  #pragma unroll
  for (int c = 0; c < 2; ++c) {
    bf16x8 wbc = Wbc8[n1 * 8 + 4 * c + g];
    bf16x8 w1d = W1dt8[n1 * 8 + 4 * c + g];
    float4 e0 = *(const float4*)&em[(size_t)b * DD + 32 * c + 8 * g];
    float4 e1 = *(const float4*)&em[(size_t)b * DD + 32 * c + 8 * g + 4];
    bB[c][0] = (bf16_t)((float)wbc[0] + e0.x * (float)w1d[0]);
    bB[c][1] = (bf16_t)((float)wbc[1] + e0.y * (float)w1d[1]);
    bB[c][2] = (bf16_t)((float)wbc[2] + e0.z * (float)w1d[2]);
    bB[c][3] = (bf16_t)((float)wbc[3] + e0.w * (float)w1d[3]);
    bB[c][4] = (bf16_t)((float)wbc[4] + e1.x * (float)w1d[4]);
    bB[c][5] = (bf16_t)((float)wbc[5] + e1.y * (float)w1d[5]);
    bB[c][6] = (bf16_t)((float)wbc[6] + e1.z * (float)w1d[6]);
    bB[c][7] = (bf16_t)((float)wbc[7] + e1.w * (float)w1d[7]);
  }
  bf16x8 bW2f[2][2];
  #pragma unroll
  for (int c = 0; c < 2; ++c)
    #pragma unroll
    for (int u = 0; u < 2; ++u)
      bW2f[c][u] = W2t8[(16 * u + l16) * 8 + 4 * c + g];

  const float qn   = Q[(size_t)b * DD + n1];
  const float b2v0 = b2[l16], b2v1 = b2[16 + l16];
  const float w3v0 = W3[l16], w3v1 = W3[16 + l16];
  const float b3s  = b3[0];

  // ---- stage Xu -> LDS (bf16) + keep in registers for pooling ----
  const float4* Xr = (const float4*)(Xu + (size_t)b * SEQ * DD);
  bf16x4 xr[13];
  #pragma unroll
  for (int k = 0; k < 13; ++k) {
    int v = tid + 256 * k;
    if (v < SEQ * DD / 4) {
      int s  = v >> 4;
      int c4 = (v & 15) * 4;
      float4 x = Xr[v];
      bf16x4 xa;
      xa[0] = (bf16_t)x.x; xa[1] = (bf16_t)x.y;
      xa[2] = (bf16_t)x.z; xa[3] = (bf16_t)x.w;
      xr[k] = xa;
      *(bf16x4*)&A[s * RS + c4] = xa;
    } else {
      xr[k][0] = (bf16_t)0.f; xr[k][1] = (bf16_t)0.f;
      xr[k][2] = (bf16_t)0.f; xr[k][3] = (bf16_t)0.f;
    }
  }
  __syncthreads();

  // ---- stage 1: h1 = relu(Xu @ B' + qn), tile-by-tile, h1 overwrites A ----
  for (int t = 0; t < 13; ++t) {
    int rb = (16 * t + l16) * RS + 8 * g;
    bf16x8 a0 = *(const bf16x8*)&A[rb];
    bf16x8 a1 = *(const bf16x8*)&A[rb + 32];
    f32x4 a = {0.f, 0.f, 0.f, 0.f};
    a = MFMA(a0, bB[0], a);
    a = MFMA(a1, bB[1], a);
    __syncthreads();   // all waves done reading tile t before overwriting it
    #pragma unroll
    for (int r = 0; r < 4; ++r) {
      float v = a[r] + qn;
      v = v > 0.f ? v : 0.f;
      A[(16 * t + 4 * g + r) * RS + n1] = (bf16_t)v;
    }
  }
  __syncthreads();

  // ---- stage 2 (K=64, N=32) + stage 3 dot -> logits ----
  for (int t = wid; t < 13; t += 4) {
    int rb = (16 * t + l16) * RS + 8 * g;
    bf16x8 h0 = *(const bf16x8*)&A[rb];
    bf16x8 h1 = *(const bf16x8*)&A[rb + 32];
    f32x4 a0 = {0.f, 0.f, 0.f, 0.f}, a1 = {0.f, 0.f, 0.f, 0.f};
    a0 = MFMA(h0, bW2f[0][0], a0);
    a0 = MFMA(h1, bW2f[1][0], a0);
    a1 = MFMA(h0, bW2f[0][1], a1);
    a1 = MFMA(h1, bW2f[1][1], a1);
    #pragma unroll
    for (int r = 0; r < 4; ++r) {
      float p0 = fmaxf(a0[r] + b2v0, 0.f) * w3v0;
      float p1 = fmaxf(a1[r] + b2v1, 0.f) * w3v1;
      float pr = p0 + p1;
      pr += __shfl_xor(pr, 1);
      pr += __shfl_xor(pr, 2);
      pr += __shfl_xor(pr, 4);
      pr += __shfl_xor(pr, 8);
      if (l16 == 0) logits[16 * t + 4 * g + r] = pr + b3s;
    }
  }
  __syncthreads();

  // ---- softmax over s < 200 ----
  float lv = (tid < SEQ) ? logits[tid] : -INFINITY;
  float mx = lv;
  #pragma unroll
  for (int o = 32; o > 0; o >>= 1) mx = fmaxf(mx, __shfl_xor(mx, o));
  if (lane == 0) red[wid] = mx;
  __syncthreads();
  mx = fmaxf(fmaxf(red[0], red[1]), fmaxf(red[2], red[3]));
  float e = (tid < SEQ) ? __expf(lv - mx) : 0.f;
  float ssum = e;
  #pragma unroll
  for (int o = 32; o > 0; o >>= 1) ssum += __shfl_xor(ssum, o);
  if (lane == 0) red[4 + wid] = ssum;
  __syncthreads();
  float inv = 1.f / (red[4] + red[5] + red[6] + red[7]);
  if (tid < SEQ) logits[tid] = e * inv;
  __syncthreads();   // also: all waves past their H reads; A reusable as `part`

  // ---- pooling from Xu registers ----
  {
    float4 ps = {0.f, 0.f, 0.f, 0.f};
    #pragma unroll
    for (int k = 0; k < 13; ++k) {
      int v = tid + 256 * k;
      if (v < SEQ * DD / 4) {
        float w = logits[(tid >> 4) + 16 * k];
        ps.x += w * (float)xr[k][0];
        ps.y += w * (float)xr[k][1];
        ps.z += w * (float)xr[k][2];
        ps.w += w * (float)xr[k][3];
      }
    }
    *(float4*)&part[(tid >> 4) * 68 + (tid & 15) * 4] = ps;
  }
  __syncthreads();

  // ---- reduce + BN + concat output ----
  if (tid < 192) {
    float v;
    if (tid < 128) {
      float x;
      if (tid < 64) {
        x = 0.f;
        #pragma unroll
        for (int r = 0; r < 16; ++r) x += part[r * 68 + tid];
      } else {
        x = em[(size_t)b * DD + (tid - 64)];
      }
      v = (x - mmean[tid]) * rsqrtf(mvar[tid] + 1e-3f) * gam[tid] + bet[tid];
    } else {
      v = eu[(size_t)b * DD + (tid - 128)];
    }
    out[(size_t)b * 192 + tid] = v;
  }
}

extern "C" void kernel_launch(void* const* d_in, const int* in_sizes, int n_in,
                              void* d_out, int out_size, void* d_ws, size_t ws_size,
                              hipStream_t stream) {
  const float* em = (const float*)d_in[0];
  const float* eu = (const float*)d_in[1];
  const float* Xu = (const float*)d_in[2];
  const float* W1 = (const float*)d_in[3];
  const float* b1 = (const float*)d_in[4];
  const float* W2 = (const float*)d_in[5];
  const float* b2 = (const float*)d_in[6];
  const float* W3 = (const float*)d_in[7];
  const float* b3 = (const float*)d_in[8];
  const float* ga = (const float*)d_in[9];
  const float* be = (const float*)d_in[10];
  const float* mm = (const float*)d_in[11];
  const float* mv = (const float*)d_in[12];
  int B = in_sizes[0] / DD;

  // workspace layout
  float*  Q    = (float*)d_ws;                               // B*64*4   = 1 MB
  bf16_t* Wbc  = (bf16_t*)((char*)d_ws + (size_t)B * 64 * 4);
  bf16_t* W1dt = Wbc  + 64 * 64;
  bf16_t* W2t  = W1dt + 64 * 64;

  prep_kernel<<<1 + B / 4, 256, 0, stream>>>(em, W1, b1, W2, Wbc, W1dt, W2t, Q);
  din_kernel<<<B, 256, 0, stream>>>(em, eu, Xu, b2, W3, b3, ga, be, mm, mv,
                                    Wbc, W1dt, W2t, Q, (float*)d_out);
}

// Round 3
// 326.470 us; speedup vs baseline: 1.2314x; 1.0187x over previous
//
#include <hip/hip_runtime.h>
#include <hip/hip_bf16.h>
#include <math.h>

typedef __bf16 bf16_t;
typedef bf16_t bf16x4 __attribute__((ext_vector_type(4)));
typedef bf16_t bf16x8 __attribute__((ext_vector_type(8)));
typedef float  f32x4  __attribute__((ext_vector_type(4)));

#define SEQ 200
#define SP  208   // 13 * 16
#define DD  64
#define RS  72    // LDS row stride (144 B): 16B-aligned b128, 2-way banks = free

#define MFMA(a, b, c) __builtin_amdgcn_mfma_f32_16x16x32_bf16((a), (b), (c), 0, 0, 0)

// ---------------- prep kernel: weight fragments (bf16, transposed) + Q ----------------
__global__ __launch_bounds__(256) void prep_kernel(
    const float* __restrict__ em, const float* __restrict__ W1,
    const float* __restrict__ b1, const float* __restrict__ W2,
    bf16_t* __restrict__ Wbc, bf16_t* __restrict__ W1dt,
    bf16_t* __restrict__ W2t, float* __restrict__ Q)
{
  const int tid = threadIdx.x;
  if (blockIdx.x == 0) {
    for (int i = tid; i < 64 * 64; i += 256) {
      int n = i >> 6, k = i & 63;
      Wbc[i]  = (bf16_t)(W1[(64 + k) * 64 + n] - W1[(128 + k) * 64 + n]);
      W1dt[i] = (bf16_t)(W1[(192 + k) * 64 + n]);
    }
    for (int i = tid; i < 32 * 64; i += 256) {
      int n = i >> 6, k = i & 63;
      W2t[i] = (bf16_t)(W2[k * 32 + n]);
    }
  } else {
    int b = (blockIdx.x - 1) * 4 + (tid >> 6);
    int n = tid & 63;
    float acc = b1[n];
    for (int d = 0; d < 64; ++d)
      acc += em[(size_t)b * 64 + d] * (W1[d * 64 + n] + W1[(128 + d) * 64 + n]);
    Q[(size_t)b * 64 + n] = acc;
  }
}

// ---------------- main kernel: one block per batch row ----------------
__global__ __launch_bounds__(256, 4) void din_kernel(
    const float* __restrict__ em, const float* __restrict__ eu,
    const float* __restrict__ Xu, const float* __restrict__ b2,
    const float* __restrict__ W3, const float* __restrict__ b3,
    const float* __restrict__ gam, const float* __restrict__ bet,
    const float* __restrict__ mmean, const float* __restrict__ mvar,
    const bf16_t* __restrict__ Wbc, const bf16_t* __restrict__ W1dt,
    const bf16_t* __restrict__ W2t, const float* __restrict__ Q,
    float* __restrict__ out)
{
  // A: Xu (bf16) -> recycled as h1 buffer -> recycled as pooling scratch
  __shared__ __align__(16) bf16_t A[SP * RS];          // 29952 B
  __shared__ float logits[SP];
  __shared__ float red[8];
  float* part = (float*)A;                             // overlay after stage-2

  const int tid  = threadIdx.x;
  const int b    = blockIdx.x;
  const int lane = tid & 63;
  const int wid  = tid >> 6;
  const int g    = lane >> 4;
  const int l16  = lane & 15;
  const int n1   = 16 * wid + l16;

  // zero the pad rows (s = 200..207)
  for (int i = tid; i < 8 * DD; i += 256) {
    int r = SEQ + (i >> 6), c = i & 63;
    A[r * RS + c] = (bf16_t)0.f;
  }

  // ---- batched global loads of Xu (one vmcnt drain, not 13 serial chains) ----
  const float4* Xr = (const float4*)(Xu + (size_t)b * SEQ * DD);
  float4 xg[13];
  #pragma unroll
  for (int k = 0; k < 12; ++k) xg[k] = Xr[tid + 256 * k];
  xg[12] = (tid < 128) ? Xr[tid + 3072] : make_float4(0.f, 0.f, 0.f, 0.f);

  // ---- fragments from precomputed transposed bf16 weights ----
  const bf16x8* Wbc8  = (const bf16x8*)Wbc;
  const bf16x8* W1dt8 = (const bf16x8*)W1dt;
  const bf16x8* W2t8  = (const bf16x8*)W2t;
  bf16x8 bB[2];
  #pragma unroll
  for (int c = 0; c < 2; ++c) {
    bf16x8 wbc = Wbc8[n1 * 8 + 4 * c + g];
    bf16x8 w1d = W1dt8[n1 * 8 + 4 * c + g];
    float4 e0 = *(const float4*)&em[(size_t)b * DD + 32 * c + 8 * g];
    float4 e1 = *(const float4*)&em[(size_t)b * DD + 32 * c + 8 * g + 4];
    bB[c][0] = (bf16_t)((float)wbc[0] + e0.x * (float)w1d[0]);
    bB[c][1] = (bf16_t)((float)wbc[1] + e0.y * (float)w1d[1]);
    bB[c][2] = (bf16_t)((float)wbc[2] + e0.z * (float)w1d[2]);
    bB[c][3] = (bf16_t)((float)wbc[3] + e0.w * (float)w1d[3]);
    bB[c][4] = (bf16_t)((float)wbc[4] + e1.x * (float)w1d[4]);
    bB[c][5] = (bf16_t)((float)wbc[5] + e1.y * (float)w1d[5]);
    bB[c][6] = (bf16_t)((float)wbc[6] + e1.z * (float)w1d[6]);
    bB[c][7] = (bf16_t)((float)wbc[7] + e1.w * (float)w1d[7]);
  }
  const float qn   = Q[(size_t)b * DD + n1];
  const float b2v0 = b2[l16], b2v1 = b2[16 + l16];
  const float w3v0 = W3[l16], w3v1 = W3[16 + l16];
  const float b3s  = b3[0];

  // ---- convert + stage to LDS, keep bf16 copy in registers for pooling ----
  bf16x4 xr[13];
  #pragma unroll
  for (int k = 0; k < 13; ++k) {
    bf16x4 xa;
    xa[0] = (bf16_t)xg[k].x; xa[1] = (bf16_t)xg[k].y;
    xa[2] = (bf16_t)xg[k].z; xa[3] = (bf16_t)xg[k].w;
    xr[k] = xa;
    int v = tid + 256 * k;
    if (v < SEQ * DD / 4)
      *(bf16x4*)&A[(v >> 4) * RS + (v & 15) * 4] = xa;
  }
  __syncthreads();  // barrier 1: A staged

  // ---- stage 1: read all tiles, accumulate; then one barrier; then write h1 ----
  f32x4 acc[13];
  #pragma unroll
  for (int t = 0; t < 13; ++t) {
    int rb = (16 * t + l16) * RS + 8 * g;
    bf16x8 a0 = *(const bf16x8*)&A[rb];
    bf16x8 a1 = *(const bf16x8*)&A[rb + 32];
    f32x4 a = {0.f, 0.f, 0.f, 0.f};
    a = MFMA(a0, bB[0], a);
    a = MFMA(a1, bB[1], a);
    acc[t] = a;
  }
  __syncthreads();  // barrier 2: all reads of Xu tiles done

  #pragma unroll
  for (int t = 0; t < 13; ++t)
    #pragma unroll
    for (int r = 0; r < 4; ++r) {
      float v = acc[t][r] + qn;
      v = v > 0.f ? v : 0.f;
      A[(16 * t + 4 * g + r) * RS + n1] = (bf16_t)v;
    }
  __syncthreads();  // barrier 3: h1 ready

  // ---- stage 2 (K=64, N=32) + stage 3 dot -> logits ----
  bf16x8 bW2f[2][2];
  #pragma unroll
  for (int c = 0; c < 2; ++c)
    #pragma unroll
    for (int u = 0; u < 2; ++u)
      bW2f[c][u] = W2t8[(16 * u + l16) * 8 + 4 * c + g];

  for (int t = wid; t < 13; t += 4) {
    int rb = (16 * t + l16) * RS + 8 * g;
    bf16x8 h0 = *(const bf16x8*)&A[rb];
    bf16x8 h1 = *(const bf16x8*)&A[rb + 32];
    f32x4 a0 = {0.f, 0.f, 0.f, 0.f}, a1 = {0.f, 0.f, 0.f, 0.f};
    a0 = MFMA(h0, bW2f[0][0], a0);
    a0 = MFMA(h1, bW2f[1][0], a0);
    a1 = MFMA(h0, bW2f[0][1], a1);
    a1 = MFMA(h1, bW2f[1][1], a1);
    #pragma unroll
    for (int r = 0; r < 4; ++r) {
      float p0 = fmaxf(a0[r] + b2v0, 0.f) * w3v0;
      float p1 = fmaxf(a1[r] + b2v1, 0.f) * w3v1;
      float pr = p0 + p1;
      pr += __shfl_xor(pr, 1);
      pr += __shfl_xor(pr, 2);
      pr += __shfl_xor(pr, 4);
      pr += __shfl_xor(pr, 8);
      if (l16 == 0) logits[16 * t + 4 * g + r] = pr + b3s;
    }
  }
  __syncthreads();  // barrier 4: logits ready (A free hereafter)

  // ---- softmax over s < 200 (e stored in logits; 1/sum folded into pooling) ----
  float lv = (tid < SEQ) ? logits[tid] : -INFINITY;
  float mx = lv;
  #pragma unroll
  for (int o = 32; o > 0; o >>= 1) mx = fmaxf(mx, __shfl_xor(mx, o));
  if (lane == 0) red[wid] = mx;
  __syncthreads();  // barrier 5
  mx = fmaxf(fmaxf(red[0], red[1]), fmaxf(red[2], red[3]));
  float e = (tid < SEQ) ? __expf(lv - mx) : 0.f;
  if (tid < SEQ) logits[tid] = e;
  float ssum = e;
  #pragma unroll
  for (int o = 32; o > 0; o >>= 1) ssum += __shfl_xor(ssum, o);
  if (lane == 0) red[4 + wid] = ssum;
  __syncthreads();  // barrier 6: e in logits, partial sums in red
  const float inv = 1.f / (red[4] + red[5] + red[6] + red[7]);

  // ---- pooling from Xu registers ----
  {
    float4 ps = {0.f, 0.f, 0.f, 0.f};
    #pragma unroll
    for (int k = 0; k < 13; ++k) {
      int v = tid + 256 * k;
      if (v < SEQ * DD / 4) {
        float w = logits[(tid >> 4) + 16 * k] * inv;
        ps.x += w * (float)xr[k][0];
        ps.y += w * (float)xr[k][1];
        ps.z += w * (float)xr[k][2];
        ps.w += w * (float)xr[k][3];
      }
    }
    *(float4*)&part[(tid >> 4) * 68 + (tid & 15) * 4] = ps;
  }
  __syncthreads();  // barrier 7: partials in LDS

  // ---- reduce + BN + concat output ----
  if (tid < 192) {
    float v;
    if (tid < 128) {
      float x;
      if (tid < 64) {
        x = 0.f;
        #pragma unroll
        for (int r = 0; r < 16; ++r) x += part[r * 68 + tid];
      } else {
        x = em[(size_t)b * DD + (tid - 64)];
      }
      v = (x - mmean[tid]) * rsqrtf(mvar[tid] + 1e-3f) * gam[tid] + bet[tid];
    } else {
      v = eu[(size_t)b * DD + (tid - 128)];
    }
    out[(size_t)b * 192 + tid] = v;
  }
}

extern "C" void kernel_launch(void* const* d_in, const int* in_sizes, int n_in,
                              void* d_out, int out_size, void* d_ws, size_t ws_size,
                              hipStream_t stream) {
  const float* em = (const float*)d_in[0];
  const float* eu = (const float*)d_in[1];
  const float* Xu = (const float*)d_in[2];
  const float* W1 = (const float*)d_in[3];
  const float* b1 = (const float*)d_in[4];
  const float* W2 = (const float*)d_in[5];
  const float* b2 = (const float*)d_in[6];
  const float* W3 = (const float*)d_in[7];
  const float* b3 = (const float*)d_in[8];
  const float* ga = (const float*)d_in[9];
  const float* be = (const float*)d_in[10];
  const float* mm = (const float*)d_in[11];
  const float* mv = (const float*)d_in[12];
  int B = in_sizes[0] / DD;

  float*  Q    = (float*)d_ws;
  bf16_t* Wbc  = (bf16_t*)((char*)d_ws + (size_t)B * 64 * 4);
  bf16_t* W1dt = Wbc  + 64 * 64;
  bf16_t* W2t  = W1dt + 64 * 64;

  prep_kernel<<<1 + B / 4, 256, 0, stream>>>(em, W1, b1, W2, Wbc, W1dt, W2t, Q);
  din_kernel<<<B, 256, 0, stream>>>(em, eu, Xu, b2, W3, b3, ga, be, mm, mv,
                                    Wbc, W1dt, W2t, Q, (float*)d_out);
}